// Round 10
// baseline (2188.614 us; speedup 1.0000x reference)
//
#include <hip/hip_runtime.h>

// ---------------------------------------------------------------------------
// TransformerDecoder forward on MI355X (gfx950) — round 10.
// = round 7 (PASS baseline) + split-K Q2/KV2 projections with elementwise
// reduce kernels (q2red/kv2red). Folded-skew experiment (r8/r9) retired:
// bit-identical 0.375 absmax with/without bf16-residual isolated it as the
// fault. PE GEMM + PEP buffer restored to the r7 proven form.
// ---------------------------------------------------------------------------

typedef unsigned short u16;
typedef short s16x8 __attribute__((ext_vector_type(8)));
typedef unsigned short u16x4 __attribute__((ext_vector_type(4)));
typedef unsigned short u16x8 __attribute__((ext_vector_type(8)));
typedef float f32x4 __attribute__((ext_vector_type(4)));

#define PADTOK 2
#define NEG_INF (-__builtin_inff())

static __device__ __forceinline__ u16 f2bf(float f) {
  unsigned u = __float_as_uint(f);
  u += 0x7fffu + ((u >> 16) & 1u);
  return (u16)(u >> 16);
}
static __device__ __forceinline__ float bf2f(u16 h) {
  return __uint_as_float(((unsigned)h) << 16);
}
static __device__ __forceinline__ float f16tof(u16 h) {
  _Float16 x = __builtin_bit_cast(_Float16, h);
  return (float)x;
}
static __device__ __forceinline__ u16 ftof16(float v) {
  _Float16 x = (_Float16)v;
  return __builtin_bit_cast(u16, x);
}
static __device__ __forceinline__ f32x4 mfma16(s16x8 a, s16x8 b, f32x4 c) {
  asm("v_mfma_f32_16x16x32_bf16 %0, %1, %2, %0" : "+v"(c) : "v"(a), "v"(b));
  return c;
}
static __device__ __forceinline__ void gll16(const void* g, void* l) {
  __builtin_amdgcn_global_load_lds((const __attribute__((address_space(1))) void*)g,
                                   (__attribute__((address_space(3))) void*)l, 16, 0, 0);
}
static __device__ __forceinline__ size_t hsidx(int m, int n) {
  return ((size_t)((m >> 9) * 16 + (n >> 6))) * 32768u + (size_t)(m & 511) * 64u + (size_t)(n & 63);
}
static __device__ __forceinline__ size_t vtidx(int m, int n) {
  return ((size_t)((m >> 9) * 16 + (n >> 6))) * 65536u + (size_t)(n & 63) * 512u + (size_t)(m & 511);
}

// XCD-chunked (bijective) + m-grouped n-major rasterization.
static __device__ __forceinline__ void raster2(int& bm, int& bn, int GM0) {
  const int nm = gridDim.y, nn = gridDim.x;
  int bid = blockIdx.y * nn + blockIdx.x;
  const int nwg = nm * nn;
  const int q = nwg >> 3, r = nwg & 7;
  const int x = bid & 7, p = bid >> 3;
  bid = (x < r ? x * (q + 1) : r * (q + 1) + (x - r) * q) + p;
  const int GM = nm < GM0 ? nm : GM0;
  const int pg = GM * nn;
  const int gi = bid / pg, rem = bid - gi * pg;
  const int left = nm - gi * GM;
  const int gm = left < GM ? left : GM;
  bm = gi * GM + rem % gm;
  bn = rem / gm;
}

// ---------------------------------------------------------------------------
// bf16 GEMM: C = epi(A[M,K] @ Bt[N,K]^T). BM=MFR*32, BN=128, BK=64.
// EPI: 0 plain  1 headsplit  4 QKV-fused  5 KV-fused  6 f16 out
// SKIP: 0 none  2 PE band-skip.  KSPLIT>1: blockIdx.z = k-slice.
// ---------------------------------------------------------------------------
template<int EPI, bool BF16OUT, int MFR, bool RELU, bool RESID, int SKIP, int GMT, int KSPLIT>
__global__ __launch_bounds__(256)
void bgemm(const u16* __restrict__ A, long long sAg,
           const u16* __restrict__ Bt, long long sBg,
           const float* __restrict__ bias, const float* __restrict__ bias2,
           const float* __restrict__ bias3,
           const float* __restrict__ Res,
           void* __restrict__ Cv, u16* __restrict__ C2, u16* __restrict__ C3,
           long long sCg, int ldc, int K, float scale)
{
  constexpr int BM = MFR * 32;
  __shared__ u16 As[BM * 64];
  __shared__ u16 Bs[128 * 64];
  int bmi, bni;
  raster2(bmi, bni, GMT);
  const int bm0 = bmi * BM, bn0 = bni * 128;
  if constexpr (SKIP == 2) {          // PE: tile unread iff (i0&511)+n0 <= 256
    if ((bm0 & 511) + bn0 <= 256) return;
  }
  const int gz = blockIdx.z;
  const int g = (KSPLIT > 1) ? 0 : gz;
  const int klen = K / KSPLIT;
  const int kbase = (KSPLIT > 1) ? gz * klen : 0;
  const u16* Ag = A + (size_t)g * (size_t)sAg;
  const u16* Bg = Bt + (size_t)g * (size_t)sBg;
  const int tid = threadIdx.x, l = tid & 63, w = tid >> 6;
  const int wm = w >> 1, wn = w & 1;
  const int rsel = l & 15, kg = l >> 4, xs = l & 7;

  f32x4 acc[MFR][4];
#pragma unroll
  for (int i = 0; i < MFR; ++i)
#pragma unroll
    for (int j = 0; j < 4; ++j) acc[i][j] = (f32x4){0.f, 0.f, 0.f, 0.f};

  const int srow = l >> 3;               // row within 8-row group
  const int sch  = (l & 7) ^ srow;       // swizzled source chunk
  const u16* Agp = Ag + ((size_t)(bm0 + w * 8 * MFR + srow)) * (size_t)K + sch * 8;
  const u16* Bgp = Bg + ((size_t)(bn0 + w * 32 + srow)) * (size_t)K + sch * 8;
  char* AsL = (char*)As + (w * 8 * MFR) * 128;
  char* BsL = (char*)Bs + (w * 32) * 128;

  for (int k0 = kbase; k0 < kbase + klen; k0 += 64) {
    __syncthreads();
#pragma unroll
    for (int i = 0; i < MFR; ++i)
      gll16(Agp + (size_t)i * 8 * K + k0, AsL + i * 1024);
#pragma unroll
    for (int i = 0; i < 4; ++i)
      gll16(Bgp + (size_t)i * 8 * K + k0, BsL + i * 1024);
    __syncthreads();

    const int arow0 = (wm * (MFR * 16) + rsel) * 128;
    const int brow0 = (wn * 64 + rsel) * 128;
#pragma unroll
    for (int ks = 0; ks < 2; ++ks) {
      const int ch = ((ks * 4 + kg) ^ xs) * 16;
      s16x8 af[MFR], bfr[4];
#pragma unroll
      for (int mf = 0; mf < MFR; ++mf)
        af[mf] = *(const s16x8*)((const char*)As + arow0 + mf * 2048 + ch);
#pragma unroll
      for (int nf = 0; nf < 4; ++nf)
        bfr[nf] = *(const s16x8*)((const char*)Bs + brow0 + nf * 2048 + ch);
#pragma unroll
      for (int mf = 0; mf < MFR; ++mf)
#pragma unroll
        for (int nf = 0; nf < 4; ++nf)
          acc[mf][nf] = mfma16(af[mf], bfr[nf], acc[mf][nf]);
    }
  }

  // epilogue: C/D layout col=lane&15 (n), row=(lane>>4)*4+e (m)
#pragma unroll
  for (int mf = 0; mf < MFR; ++mf) {
#pragma unroll
    for (int nf = 0; nf < 4; ++nf) {
      const int n = bn0 + wn * 64 + nf * 16 + rsel;
      int sub = 0, nl = n;
      const float* bp = bias;
      if constexpr (EPI == 4) {
        sub = n >> 10; nl = n & 1023;
        bp = (sub == 0) ? bias : (sub == 1) ? bias2 : bias3;
      }
      if constexpr (EPI == 5) {
        sub = n >> 10; nl = n & 1023;
        bp = (sub == 0) ? bias : bias2;
      }
      const float bv = bp ? bp[nl] : 0.f;
      float sc = 1.f;
      if constexpr (EPI == 0 || EPI == 1) sc = scale;
      if constexpr (EPI == 4) sc = (sub == 0) ? scale : 1.f;
#pragma unroll
      for (int e = 0; e < 4; ++e) {
        const int m = bm0 + wm * (MFR * 16) + mf * 16 + kg * 4 + e;
        float v = (acc[mf][nf][e] + bv) * sc;
        if constexpr (RELU) v = fmaxf(v, 0.f);
        if constexpr (RESID) v += Res[(size_t)m * (size_t)ldc + n];
        if constexpr (EPI == 0) {
          const size_t idx = (size_t)gz * (size_t)sCg + (size_t)m * (size_t)ldc + n;
          if constexpr (BF16OUT) ((u16*)Cv)[idx] = f2bf(v);
          else                   ((float*)Cv)[idx] = v;
        } else if constexpr (EPI == 1) {
          ((u16*)Cv)[hsidx(m, nl)] = f2bf(v);
        } else if constexpr (EPI == 4) {
          if (sub == 2)      C3[vtidx(m, nl)] = f2bf(v);
          else if (sub == 1) C2[hsidx(m, nl)] = f2bf(v);
          else               ((u16*)Cv)[hsidx(m, nl)] = f2bf(v);
        } else if constexpr (EPI == 5) {
          if (sub == 0) ((u16*)Cv)[hsidx(m, nl)] = f2bf(v);
          else          C2[vtidx(m, nl)] = f2bf(v);
        } else if constexpr (EPI == 6) {
          ((u16*)Cv)[(size_t)m * (size_t)ldc + n] = ftof16(v);
        }
      }
    }
  }
}

// ---------------------------------------------------------------------------
// fused attention, wave-independent — round-7 proven form.
// ---------------------------------------------------------------------------
template<bool SELF>
__global__ __launch_bounds__(256)
void fused_attn(const u16* __restrict__ Qb, const u16* __restrict__ Kb,
                const u16* __restrict__ Vt, const u16* __restrict__ PE,
                const float* __restrict__ maskf, u16* __restrict__ O)
{
  __shared__ u16 SP[4][16][520];       // per-wave score strip
  __shared__ float rsm[4][16];         // per-wave 1/rowsum
  const int bid = blockIdx.y * 8 + blockIdx.x;
  const int g = (bid & 7) + 8 * ((bid >> 3) & 7);
  const int rt = bid >> 6;             // 0..7
  const int b = g >> 4, h = g & 15;
  const int tid = threadIdx.x, l = tid & 63, w = tid >> 6;
  const int ti = SELF ? (w * 8 + rt) : (rt * 4 + w);   // row-tile 0..31
  const int i0 = ti * 16;
  const int CT = SELF ? (i0 + 16) : 512;
  const int rsel = l & 15, kg = l >> 4;

  const u16* Qg = Qb + (size_t)g * 32768u;
  const u16* Kg = Kb + (size_t)g * 32768u;
  const u16* Vg = Vt + (size_t)g * 65536u;
  u16 (*sp)[520] = SP[w];
  float* rs = rsm[w];

  const s16x8 qf0 = *(const s16x8*)(Qg + (size_t)(i0 + rsel) * 64u + kg * 8);
  const s16x8 qf1 = *(const s16x8*)(Qg + (size_t)(i0 + rsel) * 64u + 32 + kg * 8);

  // ---- QK^T (+ mask + skew + causal) -> SP ----
  for (int j0 = 0; j0 < CT; j0 += 16) {
    const s16x8 kf0 = *(const s16x8*)(Kg + (size_t)(j0 + rsel) * 64u + kg * 8);
    const s16x8 kf1 = *(const s16x8*)(Kg + (size_t)(j0 + rsel) * 64u + 32 + kg * 8);
    f32x4 a = {0.f, 0.f, 0.f, 0.f};
    a = mfma16(qf0, kf0, a);
    a = mfma16(qf1, kf1, a);
    const int jj = j0 + rsel;                   // output col = l&15
    const float mj = maskf[b * 512 + jj];
#pragma unroll
    for (int e = 0; e < 4; ++e) {
      const int r = kg * 4 + e;                 // local q-row (output row)
      float v = a[e] + mj;
      if constexpr (SELF) {
        const int i = i0 + r;
        if (jj > i) v = NEG_INF;
        else        v += bf2f(PE[((size_t)(g * 512 + i)) * 512u + (511 + jj - i)]);
      }
      sp[r][jj] = f2bf(v);
    }
  }
  asm volatile("s_waitcnt lgkmcnt(0)" ::: "memory");
  __builtin_amdgcn_sched_barrier(0);

  // ---- softmax (wave-local): 4 lanes per row ----
  const int sr = l >> 2, sub = l & 3;
  float mx = NEG_INF;
  for (int c = sub * 4; c < CT; c += 16) {
    const u16x4 h4 = *(const u16x4*)&sp[sr][c];
#pragma unroll
    for (int e = 0; e < 4; ++e) mx = fmaxf(mx, bf2f(h4[e]));
  }
  mx = fmaxf(mx, __shfl_xor(mx, 1, 64));
  mx = fmaxf(mx, __shfl_xor(mx, 2, 64));
  float sum = 0.f;
  for (int c = sub * 4; c < CT; c += 16) {
    const u16x4 h4 = *(const u16x4*)&sp[sr][c];
    const float p0 = expf(bf2f(h4[0]) - mx), p1 = expf(bf2f(h4[1]) - mx);
    const float p2 = expf(bf2f(h4[2]) - mx), p3 = expf(bf2f(h4[3]) - mx);
    sum += p0 + p1 + p2 + p3;
    const u16x4 o4 = {f2bf(p0), f2bf(p1), f2bf(p2), f2bf(p3)};
    *(u16x4*)&sp[sr][c] = o4;                  // unnormalized P
  }
  sum += __shfl_xor(sum, 1, 64);
  sum += __shfl_xor(sum, 2, 64);
  if (sub == 0) rs[sr] = 1.f / sum;
  if (CT & 31) {                               // zero-pad P to 32-col boundary
    const u16x4 z = {0, 0, 0, 0};
    *(u16x4*)&sp[sr][CT + sub * 4] = z;
  }
  asm volatile("s_waitcnt lgkmcnt(0)" ::: "memory");
  __builtin_amdgcn_sched_barrier(0);

  // ---- PV: O[16][64] accumulated in registers ----
  f32x4 oa[4];
#pragma unroll
  for (int nt = 0; nt < 4; ++nt) oa[nt] = (f32x4){0.f, 0.f, 0.f, 0.f};
  const int nk = (CT + 31) >> 5;
  for (int kt = 0; kt < nk; ++kt) {
    const s16x8 pf = *(const s16x8*)&sp[rsel][kt * 32 + kg * 8];
#pragma unroll
    for (int nt = 0; nt < 4; ++nt) {
      const s16x8 vf = *(const s16x8*)(Vg + (size_t)(nt * 16 + rsel) * 512u + kt * 32 + kg * 8);
      oa[nt] = mfma16(pf, vf, oa[nt]);
    }
  }

  // ---- normalize + merged-head write ----
#pragma unroll
  for (int e = 0; e < 4; ++e) {
    const int q = kg * 4 + e;                  // local row
    const float inv = rs[q];
    u16* orow = O + ((size_t)(b * 512 + i0 + q)) * 1024u + h * 64;
#pragma unroll
    for (int nt = 0; nt < 4; ++nt)
      orow[nt * 16 + rsel] = f2bf(oa[nt][e] * inv);
  }
}

// ---------------------------------------------------------------------------
// split-K reduce + bias + residual(f32) + LayerNorm -> f32 Y + bf16 Yh
// ---------------------------------------------------------------------------
template<int KS>
__global__ __launch_bounds__(256)
void lnred_kernel(const float* __restrict__ P, const float* __restrict__ bias,
                  const float* __restrict__ R,
                  const float* __restrict__ gw, const float* __restrict__ bw,
                  float* __restrict__ Y, u16* __restrict__ Yh)
{
  __shared__ float sm[4];
  const int m = blockIdx.x, t = threadIdx.x, c = t * 4;
  float4 v = *(const float4*)(R + (size_t)m * 1024u + c);
  const float4 bb = *(const float4*)(bias + c);
  v.x += bb.x; v.y += bb.y; v.z += bb.z; v.w += bb.w;
#pragma unroll
  for (int s = 0; s < KS; ++s) {
    const float4 p = *(const float4*)(P + (size_t)s * 2097152u + (size_t)m * 1024u + c);
    v.x += p.x; v.y += p.y; v.z += p.z; v.w += p.w;
  }
  float srow = v.x + v.y + v.z + v.w;
  {  // block reduce sum
    const int lane = t & 63, wid = t >> 6;
    float r = srow;
#pragma unroll
    for (int o = 32; o > 0; o >>= 1) r += __shfl_down(r, o, 64);
    if (lane == 0) sm[wid] = r;
    __syncthreads();
    if (t == 0) sm[0] = sm[0] + sm[1] + sm[2] + sm[3];
    __syncthreads();
    srow = sm[0];
    __syncthreads();
  }
  const float mean = srow * (1.f / 1024.f);
  const float d0 = v.x - mean, d1 = v.y - mean, d2 = v.z - mean, d3 = v.w - mean;
  float q = d0 * d0 + d1 * d1 + d2 * d2 + d3 * d3;
  {
    const int lane = t & 63, wid = t >> 6;
    float r = q;
#pragma unroll
    for (int o = 32; o > 0; o >>= 1) r += __shfl_down(r, o, 64);
    if (lane == 0) sm[wid] = r;
    __syncthreads();
    if (t == 0) sm[0] = sm[0] + sm[1] + sm[2] + sm[3];
    __syncthreads();
    q = sm[0];
    __syncthreads();
  }
  const float rstd = rsqrtf(q * (1.f / 1024.f) + 1e-5f);
  float4 o;
  o.x = d0 * rstd * gw[c + 0] + bw[c + 0];
  o.y = d1 * rstd * gw[c + 1] + bw[c + 1];
  o.z = d2 * rstd * gw[c + 2] + bw[c + 2];
  o.w = d3 * rstd * gw[c + 3] + bw[c + 3];
  *(float4*)(Y + (size_t)m * 1024u + c) = o;
  const u16x4 h = {f2bf(o.x), f2bf(o.y), f2bf(o.z), f2bf(o.w)};
  *(u16x4*)(Yh + (size_t)m * 1024u + c) = h;
}

// ---------------------------------------------------------------------------
// split-K reduces for Q2 / KV2 projections (elementwise, verified indices)
// ---------------------------------------------------------------------------
__global__ __launch_bounds__(256)
void q2red_kernel(const float* __restrict__ P, const float* __restrict__ bias,
                  u16* __restrict__ Q) {
  const int m = blockIdx.x, t = threadIdx.x, c = t * 4;
  const float4 p0 = *(const float4*)(P + (size_t)m * 1024u + c);
  const float4 p1 = *(const float4*)(P + 2097152u + (size_t)m * 1024u + c);
  const float4 bb = *(const float4*)(bias + c);
  const u16x4 h = {f2bf((p0.x + p1.x + bb.x) * 0.125f),
                   f2bf((p0.y + p1.y + bb.y) * 0.125f),
                   f2bf((p0.z + p1.z + bb.z) * 0.125f),
                   f2bf((p0.w + p1.w + bb.w) * 0.125f)};
  *(u16x4*)(Q + hsidx(m, c)) = h;
}

__global__ __launch_bounds__(256)
void kv2red_kernel(const float* __restrict__ P, const float* __restrict__ bk,
                   const float* __restrict__ bv,
                   u16* __restrict__ Kh, u16* __restrict__ VT) {
  const int m = blockIdx.x, half = blockIdx.y, t = threadIdx.x, c = t * 4;
  const int n = half * 1024 + c;
  const float4 p0 = *(const float4*)(P + (size_t)m * 2048u + n);
  const float4 p1 = *(const float4*)(P + 4194304u + (size_t)m * 2048u + n);
  if (half == 0) {
    const float4 bb = *(const float4*)(bk + c);
    const u16x4 h = {f2bf(p0.x + p1.x + bb.x), f2bf(p0.y + p1.y + bb.y),
                     f2bf(p0.z + p1.z + bb.z), f2bf(p0.w + p1.w + bb.w)};
    *(u16x4*)(Kh + hsidx(m, c)) = h;
  } else {
    const float4 bb = *(const float4*)(bv + c);
    VT[vtidx(m, c + 0)] = f2bf(p0.x + p1.x + bb.x);
    VT[vtidx(m, c + 1)] = f2bf(p0.y + p1.y + bb.y);
    VT[vtidx(m, c + 2)] = f2bf(p0.z + p1.z + bb.z);
    VT[vtidx(m, c + 3)] = f2bf(p0.w + p1.w + bb.w);
  }
}

// ---------------------------------------------------------------------------
// transpose+convert f32[K,N] -> bf16[N,K], 64x64 tiles
// ---------------------------------------------------------------------------
static __device__ __forceinline__ void tconv_tile(const float* in, int N,
                                                  u16* out, int K, int k0, int n0) {
  __shared__ u16 L[64][72];
  const int t = threadIdx.x;
  const int rk = t >> 4, cn = (t & 15) * 4;
#pragma unroll
  for (int q = 0; q < 4; ++q) {
    const int kk = k0 + rk + q * 16;
    float4 v = *(const float4*)(in + (size_t)kk * (size_t)N + n0 + cn);
    L[cn + 0][rk + q * 16] = f2bf(v.x);
    L[cn + 1][rk + q * 16] = f2bf(v.y);
    L[cn + 2][rk + q * 16] = f2bf(v.z);
    L[cn + 3][rk + q * 16] = f2bf(v.w);
  }
  __syncthreads();
  const int rn = t >> 2, ck = (t & 3) * 16;
  u16* op = out + (size_t)(n0 + rn) * (size_t)K + k0 + ck;
  *(s16x8*)op       = *(const s16x8*)&L[rn][ck];
  *(s16x8*)(op + 8) = *(const s16x8*)&L[rn][ck + 8];
}

__global__ __launch_bounds__(256)
void conv_layer(const float* w0, const float* w1, const float* w2, const float* w3,
                const float* w4, const float* w5, const float* w6, const float* w7,
                const float* w8, const float* w9, u16* WT) {
  const int b = blockIdx.x;
  const float* in; u16* out; int N, K, kt, nt;
  if (b < 2048) {
    const int j = b >> 8, t = b & 255;
    const float* ws[8] = {w0, w1, w2, w3, w4, w5, w6, w7};
    in = ws[j]; out = WT + (size_t)j * 1048576u; K = 1024; N = 1024;
    kt = t >> 4; nt = t & 15;
  } else if (b < 3072) {
    const int t = b - 2048;
    in = w8; out = WT + 8388608u; K = 1024; N = 4096; kt = t >> 6; nt = t & 63;
  } else {
    const int t = b - 3072;
    in = w9; out = WT + 12582912u; K = 4096; N = 1024; kt = t >> 4; nt = t & 15;
  }
  tconv_tile(in, N, out, K, kt * 64, nt * 64);
}

__global__ __launch_bounds__(256)
void conv_wout(const float* in, u16* out) {
  const int b = blockIdx.x;            // 8000 = 16 ktiles * 500 ntiles
  const int kt = b / 500, nt = b % 500;
  tconv_tile(in, 32000, out, 1024, kt * 64, nt * 64);
}

// ---------------------------------------------------------------------------
// elementwise converts / masks
// ---------------------------------------------------------------------------
__global__ void conv_bf16(const float* __restrict__ in, u16* __restrict__ out) {
  const int i = (blockIdx.x * 256 + threadIdx.x) * 4;
  float4 v = *(const float4*)(in + i);
  u16x4 h = {f2bf(v.x), f2bf(v.y), f2bf(v.z), f2bf(v.w)};
  *(u16x4*)(out + i) = h;
}

__global__ void conv_pos(const float* __restrict__ pos, u16* __restrict__ posb) {
  const int idx = (blockIdx.x * 256 + threadIdx.x) * 4;   // over 6*512*64
  const int lyr = idx >> 15, rem = idx & 32767;
  float4 v = *(const float4*)(pos + (size_t)lyr * 65472u + rem);
  u16x4 h = {f2bf(v.x), f2bf(v.y), f2bf(v.z), f2bf(v.w)};
  *(u16x4*)(posb + idx) = h;
}

__global__ void mask_kernel(const int* __restrict__ dec, const int* __restrict__ enc,
                            float* __restrict__ mD, float* __restrict__ mE) {
  const int i = blockIdx.x * 256 + threadIdx.x;   // 2048
  mD[i] = (dec[i] == PADTOK) ? NEG_INF : 0.f;
  mE[i] = (enc[i] == PADTOK) ? NEG_INF : 0.f;
}

// ---------------------------------------------------------------------------
// reductions
// ---------------------------------------------------------------------------
static __device__ __forceinline__ float wred_sum(float v) {
#pragma unroll
  for (int o = 32; o > 0; o >>= 1) v += __shfl_down(v, o, 64);
  return v;
}
static __device__ __forceinline__ float wred_max(float v) {
#pragma unroll
  for (int o = 32; o > 0; o >>= 1) v = fmaxf(v, __shfl_down(v, o, 64));
  return v;
}

// ---------------------------------------------------------------------------
// small kernels
// ---------------------------------------------------------------------------
__global__ void embed_kernel(const int* __restrict__ dec, const float* __restrict__ emb,
                             float* __restrict__ X, u16* __restrict__ Xh) {
  const int m = blockIdx.x, t = threadIdx.x;
  const int tok = dec[m];
  float4 v = ((const float4*)(emb + (size_t)tok * 1024u))[t];
  ((float4*)(X + (size_t)m * 1024u))[t] = v;
  u16x4 h = {f2bf(v.x), f2bf(v.y), f2bf(v.z), f2bf(v.w)};
  *(u16x4*)(Xh + (size_t)m * 1024u + t * 4) = h;
}

// log_softmax over V=32000: f16 logits in first half of each f32 out row.
__global__ __launch_bounds__(512)
void log_softmax_kernel(float* __restrict__ out) {
  __shared__ u16 row[32000];
  __shared__ float sm[8];
  const int m = blockIdx.x, tid = threadIdx.x;
  const u16* src = (const u16*)out + (size_t)m * 64000u;
  for (int c = tid; c < 4000; c += 512)
    *(u16x8*)&row[c * 8] = *(const u16x8*)(src + c * 8);
  __syncthreads();
  float mx = NEG_INF;
  for (int c = tid; c < 4000; c += 512) {
    const u16x8 h = *(const u16x8*)&row[c * 8];
#pragma unroll
    for (int e = 0; e < 8; ++e) mx = fmaxf(mx, f16tof(h[e]));
  }
  mx = wred_max(mx);
  if ((tid & 63) == 0) sm[tid >> 6] = mx;
  __syncthreads();
  if (tid == 0) {
    float a = sm[0];
#pragma unroll
    for (int wI = 1; wI < 8; ++wI) a = fmaxf(a, sm[wI]);
    sm[0] = a;
  }
  __syncthreads();
  mx = sm[0];
  __syncthreads();
  float s = 0.f;
  for (int c = tid; c < 4000; c += 512) {
    const u16x8 h = *(const u16x8*)&row[c * 8];
#pragma unroll
    for (int e = 0; e < 8; ++e) s += expf(f16tof(h[e]) - mx);
  }
  s = wred_sum(s);
  if ((tid & 63) == 0) sm[tid >> 6] = s;
  __syncthreads();
  if (tid == 0) {
    float a = 0.f;
#pragma unroll
    for (int wI = 0; wI < 8; ++wI) a += sm[wI];
    sm[0] = a;
  }
  __syncthreads();
  const float lse = mx + logf(sm[0]);
  float* dst = out + (size_t)m * 32000u;
  for (int c = tid; c < 4000; c += 512) {
    const u16x8 h = *(const u16x8*)&row[c * 8];
    float4 o0, o1;
    o0.x = f16tof(h[0]) - lse; o0.y = f16tof(h[1]) - lse;
    o0.z = f16tof(h[2]) - lse; o0.w = f16tof(h[3]) - lse;
    o1.x = f16tof(h[4]) - lse; o1.y = f16tof(h[5]) - lse;
    o1.z = f16tof(h[6]) - lse; o1.w = f16tof(h[7]) - lse;
    ((float4*)dst)[c * 2]     = o0;
    ((float4*)dst)[c * 2 + 1] = o1;
  }
}

// ---------------------------------------------------------------------------
// host driver
// ---------------------------------------------------------------------------
extern "C" void kernel_launch(void* const* d_in, const int* in_sizes, int n_in,
                              void* d_out, int out_size, void* d_ws, size_t ws_size,
                              hipStream_t stream) {
  const float* enc_out = (const float*)d_in[0];
  const int*   dec_in  = (const int*)d_in[1];
  const int*   enc_in  = (const int*)d_in[2];
  const float* emb     = (const float*)d_in[3];
  const float* wq1 = (const float*)d_in[4];  const float* bq1 = (const float*)d_in[5];
  const float* wk1 = (const float*)d_in[6];  const float* bk1 = (const float*)d_in[7];
  const float* wv1 = (const float*)d_in[8];  const float* bv1 = (const float*)d_in[9];
  const float* wo1 = (const float*)d_in[10]; const float* bo1 = (const float*)d_in[11];
  const float* pos1 = (const float*)d_in[12];
  const float* wq2 = (const float*)d_in[13]; const float* bq2 = (const float*)d_in[14];
  const float* wk2 = (const float*)d_in[15]; const float* bk2 = (const float*)d_in[16];
  const float* wv2 = (const float*)d_in[17]; const float* bv2 = (const float*)d_in[18];
  const float* wo2 = (const float*)d_in[19]; const float* bo2 = (const float*)d_in[20];
  const float* ln1g = (const float*)d_in[21]; const float* ln1b = (const float*)d_in[22];
  const float* ln2g = (const float*)d_in[23]; const float* ln2b = (const float*)d_in[24];
  const float* ln3g = (const float*)d_in[25]; const float* ln3b = (const float*)d_in[26];
  const float* wf1 = (const float*)d_in[27]; const float* bf1 = (const float*)d_in[28];
  const float* wf2 = (const float*)d_in[29]; const float* bf2 = (const float*)d_in[30];
  const float* wout = (const float*)d_in[31]; const float* bout = (const float*)d_in[32];

  char* ws = (char*)d_ws;
  u16*   WT    = (u16*)(ws + 0);             // 32MB  per-layer transposed weights
  float* maskD = (float*)(ws + 33554432);    // 8KB
  float* maskE = (float*)(ws + 33562624);    // 8KB
  u16*   WoutT = (u16*)(ws + 0);             // 65.5MB, used only at the end
  u16*   PEP   = (u16*)(ws + 67108864);      // 32MB  PE bf16 (dead after fattn_self)
  float* Part  = (float*)(ws + 67108864);    // 32MB  split-K partials (reuses PEP)
  float* X     = (float*)(ws + 100663296);   // 8MB  f32 residual stream
  float* Xa    = (float*)(ws + 109051904);   // 8MB
  float* Xb    = (float*)(ws + 117440512);   // 8MB
  u16*   Ab16  = (u16*)(ws + 134217728);     // 4MB  current GEMM-input activation
  u16*   Q     = (u16*)(ws + 138412032);     // 4MB  [g][512][64]
  u16*   Kh    = (u16*)(ws + 142606336);     // 4MB  [g][512][64]
  u16*   VT    = (u16*)(ws + 146800640);     // 8MB  [g][128][512]
  u16*   Ob16  = (u16*)(ws + 155189248);     // 4MB  merged attn out
  u16*   FFH16 = (u16*)(ws + 159383552);     // 16MB [2048][4096]
  u16*   encb  = (u16*)(ws + 176160768);     // 4MB  encoder_outputs bf16
  u16*   posb  = (u16*)(ws + 180355072);     // 384KB [6][512][64]
  float* out   = (float*)d_out;

  embed_kernel<<<2048, 256, 0, stream>>>(dec_in, emb, X, Ab16);
  conv_bf16<<<2048, 256, 0, stream>>>(enc_out, encb);
  conv_pos<<<192, 256, 0, stream>>>(pos1, posb);
  mask_kernel<<<8, 256, 0, stream>>>(dec_in, enc_in, maskD, maskE);

  for (int i = 0; i < 6; ++i) {
    const size_t oHH = (size_t)i * 1048576u, oH = (size_t)i * 1024u;
    const float* bq1i = bq1 + oH; const float* bk1i = bk1 + oH;
    const float* bv1i = bv1 + oH; const float* bo1i = bo1 + oH;
    const float* bq2i = bq2 + oH; const float* bk2i = bk2 + oH;
    const float* bv2i = bv2 + oH; const float* bo2i = bo2 + oH;
    const float* bf1i = bf1 + (size_t)i * 4096u; const float* bf2i = bf2 + oH;
    const u16* posL = posb + (size_t)i * 32768u;

    conv_layer<<<4096, 256, 0, stream>>>(
        wq1 + oHH, wk1 + oHH, wv1 + oHH, wo1 + oHH,
        wq2 + oHH, wk2 + oHH, wv2 + oHH, wo2 + oHH,
        wf1 + (size_t)i * 4194304u, wf2 + (size_t)i * 4194304u, WT);

    // ---- self attention ----
    bgemm<4, true, 4, false, false, 0, 8, 1><<<dim3(24, 16, 1), 256, 0, stream>>>(
        Ab16, 0, WT, 0, bq1i, bk1i, bv1i, nullptr, Q, Kh, VT, 0, 0, 1024, 0.125f);
    bgemm<0, true, 4, false, false, 2, 8, 1><<<dim3(4, 256, 1), 256, 0, stream>>>(
        Q, 0, posL, 0, nullptr, nullptr, nullptr, nullptr, PEP, nullptr, nullptr,
        0, 512, 64, 1.f);
    fused_attn<true><<<dim3(8, 64), 256, 0, stream>>>(Q, Kh, VT, PEP, maskD, Ob16);
    bgemm<0, false, 2, false, false, 0, 8, 2><<<dim3(8, 32, 2), 256, 0, stream>>>(
        Ob16, 0, WT + 3145728u, 0, nullptr, nullptr, nullptr, nullptr,
        Part, nullptr, nullptr, 2097152, 1024, 1024, 1.f);
    lnred_kernel<2><<<2048, 256, 0, stream>>>(Part, bo1i, X, ln1g + oH, ln1b + oH, Xa, Ab16);

    // ---- cross attention (split-K Q2 / KV2 + elementwise reduces) ----
    bgemm<0, false, 2, false, false, 0, 8, 2><<<dim3(8, 32, 2), 256, 0, stream>>>(
        Ab16, 0, WT + 4194304u, 0, nullptr, nullptr, nullptr, nullptr,
        Part, nullptr, nullptr, 2097152, 1024, 1024, 1.f);
    q2red_kernel<<<2048, 256, 0, stream>>>(Part, bq2i, Q);
    bgemm<0, false, 4, false, false, 0, 8, 2><<<dim3(16, 16, 2), 256, 0, stream>>>(
        encb, 0, WT + 5242880u, 0, nullptr, nullptr, nullptr, nullptr,
        Part, nullptr, nullptr, 4194304, 2048, 1024, 1.f);
    kv2red_kernel<<<dim3(2048, 2), 256, 0, stream>>>(Part, bk2i, bv2i, Kh, VT);
    fused_attn<false><<<dim3(8, 64), 256, 0, stream>>>(Q, Kh, VT, nullptr, maskE, Ob16);
    bgemm<0, false, 2, false, false, 0, 8, 2><<<dim3(8, 32, 2), 256, 0, stream>>>(
        Ob16, 0, WT + 7340032u, 0, nullptr, nullptr, nullptr, nullptr,
        Part, nullptr, nullptr, 2097152, 1024, 1024, 1.f);
    lnred_kernel<2><<<2048, 256, 0, stream>>>(Part, bo2i, Xa, ln2g + oH, ln2b + oH, Xb, Ab16);

    // ---- FFN ----
    bgemm<0, true, 4, true, false, 0, 8, 1><<<dim3(32, 16, 1), 256, 0, stream>>>(
        Ab16, 0, WT + 8388608u, 0, bf1i, nullptr, nullptr, nullptr, FFH16, nullptr, nullptr,
        0, 4096, 1024, 1.f);
    bgemm<0, false, 4, false, false, 0, 8, 4><<<dim3(8, 16, 4), 256, 0, stream>>>(
        FFH16, 0, WT + 12582912u, 0, nullptr, nullptr, nullptr, nullptr,
        Part, nullptr, nullptr, 2097152, 1024, 4096, 1.f);
    lnred_kernel<4><<<2048, 256, 0, stream>>>(Part, bf2i, Xb, ln3g + oH, ln3b + oH, X, Ab16);
  }

  // ---- output head (f16 logits into d_out row-halves) + log_softmax ----
  conv_wout<<<8000, 256, 0, stream>>>(wout, WoutT);
  bgemm<6, false, 4, false, false, 0, 16, 1><<<dim3(250, 16, 1), 256, 0, stream>>>(
      Ab16, 0, WoutT, 0, bout, nullptr, nullptr, nullptr, out, nullptr, nullptr,
      0, 64000, 1024, 1.f);
  log_softmax_kernel<<<2048, 512, 0, stream>>>(out);
}

// Round 11
// 2067.125 us; speedup vs baseline: 1.0588x; 1.0588x over previous
//
#include <hip/hip_runtime.h>

// ---------------------------------------------------------------------------
// TransformerDecoder forward on MI355X (gfx950) — round 11.
// Exact revert to the round-7 optimum (best verified: 2080 µs, absmax 0.0625).
// Round-10's Q2/KV2 split-K regressed (−109 µs): the added f32-partial
// round-trip (48 MB/layer) + 2 reduce dispatches cost more than the
// occupancy gain. Split-K is kept ONLY where its reduce fuses into the
// already-required LN pass (out-proj KS=2, FFN2 KS=4 -> lnred).
// Retired experiments: q2kv2-merge, fattn-setprio, folded-skew, bf16-residual.
// ---------------------------------------------------------------------------

typedef unsigned short u16;
typedef short s16x8 __attribute__((ext_vector_type(8)));
typedef unsigned short u16x4 __attribute__((ext_vector_type(4)));
typedef unsigned short u16x8 __attribute__((ext_vector_type(8)));
typedef float f32x4 __attribute__((ext_vector_type(4)));

#define PADTOK 2
#define NEG_INF (-__builtin_inff())

static __device__ __forceinline__ u16 f2bf(float f) {
  unsigned u = __float_as_uint(f);
  u += 0x7fffu + ((u >> 16) & 1u);
  return (u16)(u >> 16);
}
static __device__ __forceinline__ float bf2f(u16 h) {
  return __uint_as_float(((unsigned)h) << 16);
}
static __device__ __forceinline__ float f16tof(u16 h) {
  _Float16 x = __builtin_bit_cast(_Float16, h);
  return (float)x;
}
static __device__ __forceinline__ u16 ftof16(float v) {
  _Float16 x = (_Float16)v;
  return __builtin_bit_cast(u16, x);
}
static __device__ __forceinline__ f32x4 mfma16(s16x8 a, s16x8 b, f32x4 c) {
  asm("v_mfma_f32_16x16x32_bf16 %0, %1, %2, %0" : "+v"(c) : "v"(a), "v"(b));
  return c;
}
static __device__ __forceinline__ void gll16(const void* g, void* l) {
  __builtin_amdgcn_global_load_lds((const __attribute__((address_space(1))) void*)g,
                                   (__attribute__((address_space(3))) void*)l, 16, 0, 0);
}
static __device__ __forceinline__ size_t hsidx(int m, int n) {
  return ((size_t)((m >> 9) * 16 + (n >> 6))) * 32768u + (size_t)(m & 511) * 64u + (size_t)(n & 63);
}
static __device__ __forceinline__ size_t vtidx(int m, int n) {
  return ((size_t)((m >> 9) * 16 + (n >> 6))) * 65536u + (size_t)(n & 63) * 512u + (size_t)(m & 511);
}

// XCD-chunked (bijective) + m-grouped n-major rasterization.
static __device__ __forceinline__ void raster2(int& bm, int& bn, int GM0) {
  const int nm = gridDim.y, nn = gridDim.x;
  int bid = blockIdx.y * nn + blockIdx.x;
  const int nwg = nm * nn;
  const int q = nwg >> 3, r = nwg & 7;
  const int x = bid & 7, p = bid >> 3;
  bid = (x < r ? x * (q + 1) : r * (q + 1) + (x - r) * q) + p;
  const int GM = nm < GM0 ? nm : GM0;
  const int pg = GM * nn;
  const int gi = bid / pg, rem = bid - gi * pg;
  const int left = nm - gi * GM;
  const int gm = left < GM ? left : GM;
  bm = gi * GM + rem % gm;
  bn = rem / gm;
}

// ---------------------------------------------------------------------------
// bf16 GEMM: C = epi(A[M,K] @ Bt[N,K]^T). BM=MFR*32, BN=128, BK=64.
// EPI: 0 plain  1 headsplit  4 QKV-fused  5 KV-fused  6 f16 out
// SKIP: 0 none  2 PE band-skip.  KSPLIT>1: blockIdx.z = k-slice.
// ---------------------------------------------------------------------------
template<int EPI, bool BF16OUT, int MFR, bool RELU, bool RESID, int SKIP, int GMT, int KSPLIT>
__global__ __launch_bounds__(256)
void bgemm(const u16* __restrict__ A, long long sAg,
           const u16* __restrict__ Bt, long long sBg,
           const float* __restrict__ bias, const float* __restrict__ bias2,
           const float* __restrict__ bias3,
           const float* __restrict__ Res,
           void* __restrict__ Cv, u16* __restrict__ C2, u16* __restrict__ C3,
           long long sCg, int ldc, int K, float scale)
{
  constexpr int BM = MFR * 32;
  __shared__ u16 As[BM * 64];
  __shared__ u16 Bs[128 * 64];
  int bmi, bni;
  raster2(bmi, bni, GMT);
  const int bm0 = bmi * BM, bn0 = bni * 128;
  if constexpr (SKIP == 2) {          // PE: tile unread iff (i0&511)+n0 <= 256
    if ((bm0 & 511) + bn0 <= 256) return;
  }
  const int gz = blockIdx.z;
  const int g = (KSPLIT > 1) ? 0 : gz;
  const int klen = K / KSPLIT;
  const int kbase = (KSPLIT > 1) ? gz * klen : 0;
  const u16* Ag = A + (size_t)g * (size_t)sAg;
  const u16* Bg = Bt + (size_t)g * (size_t)sBg;
  const int tid = threadIdx.x, l = tid & 63, w = tid >> 6;
  const int wm = w >> 1, wn = w & 1;
  const int rsel = l & 15, kg = l >> 4, xs = l & 7;

  f32x4 acc[MFR][4];
#pragma unroll
  for (int i = 0; i < MFR; ++i)
#pragma unroll
    for (int j = 0; j < 4; ++j) acc[i][j] = (f32x4){0.f, 0.f, 0.f, 0.f};

  const int srow = l >> 3;               // row within 8-row group
  const int sch  = (l & 7) ^ srow;       // swizzled source chunk
  const u16* Agp = Ag + ((size_t)(bm0 + w * 8 * MFR + srow)) * (size_t)K + sch * 8;
  const u16* Bgp = Bg + ((size_t)(bn0 + w * 32 + srow)) * (size_t)K + sch * 8;
  char* AsL = (char*)As + (w * 8 * MFR) * 128;
  char* BsL = (char*)Bs + (w * 32) * 128;

  for (int k0 = kbase; k0 < kbase + klen; k0 += 64) {
    __syncthreads();
#pragma unroll
    for (int i = 0; i < MFR; ++i)
      gll16(Agp + (size_t)i * 8 * K + k0, AsL + i * 1024);
#pragma unroll
    for (int i = 0; i < 4; ++i)
      gll16(Bgp + (size_t)i * 8 * K + k0, BsL + i * 1024);
    __syncthreads();

    const int arow0 = (wm * (MFR * 16) + rsel) * 128;
    const int brow0 = (wn * 64 + rsel) * 128;
#pragma unroll
    for (int ks = 0; ks < 2; ++ks) {
      const int ch = ((ks * 4 + kg) ^ xs) * 16;
      s16x8 af[MFR], bfr[4];
#pragma unroll
      for (int mf = 0; mf < MFR; ++mf)
        af[mf] = *(const s16x8*)((const char*)As + arow0 + mf * 2048 + ch);
#pragma unroll
      for (int nf = 0; nf < 4; ++nf)
        bfr[nf] = *(const s16x8*)((const char*)Bs + brow0 + nf * 2048 + ch);
#pragma unroll
      for (int mf = 0; mf < MFR; ++mf)
#pragma unroll
        for (int nf = 0; nf < 4; ++nf)
          acc[mf][nf] = mfma16(af[mf], bfr[nf], acc[mf][nf]);
    }
  }

  // epilogue: C/D layout col=lane&15 (n), row=(lane>>4)*4+e (m)
#pragma unroll
  for (int mf = 0; mf < MFR; ++mf) {
#pragma unroll
    for (int nf = 0; nf < 4; ++nf) {
      const int n = bn0 + wn * 64 + nf * 16 + rsel;
      int sub = 0, nl = n;
      const float* bp = bias;
      if constexpr (EPI == 4) {
        sub = n >> 10; nl = n & 1023;
        bp = (sub == 0) ? bias : (sub == 1) ? bias2 : bias3;
      }
      if constexpr (EPI == 5) {
        sub = n >> 10; nl = n & 1023;
        bp = (sub == 0) ? bias : bias2;
      }
      const float bv = bp ? bp[nl] : 0.f;
      float sc = 1.f;
      if constexpr (EPI == 0 || EPI == 1) sc = scale;
      if constexpr (EPI == 4) sc = (sub == 0) ? scale : 1.f;
#pragma unroll
      for (int e = 0; e < 4; ++e) {
        const int m = bm0 + wm * (MFR * 16) + mf * 16 + kg * 4 + e;
        float v = (acc[mf][nf][e] + bv) * sc;
        if constexpr (RELU) v = fmaxf(v, 0.f);
        if constexpr (RESID) v += Res[(size_t)m * (size_t)ldc + n];
        if constexpr (EPI == 0) {
          const size_t idx = (size_t)gz * (size_t)sCg + (size_t)m * (size_t)ldc + n;
          if constexpr (BF16OUT) ((u16*)Cv)[idx] = f2bf(v);
          else                   ((float*)Cv)[idx] = v;
        } else if constexpr (EPI == 1) {
          ((u16*)Cv)[hsidx(m, nl)] = f2bf(v);
        } else if constexpr (EPI == 4) {
          if (sub == 2)      C3[vtidx(m, nl)] = f2bf(v);
          else if (sub == 1) C2[hsidx(m, nl)] = f2bf(v);
          else               ((u16*)Cv)[hsidx(m, nl)] = f2bf(v);
        } else if constexpr (EPI == 5) {
          if (sub == 0) ((u16*)Cv)[hsidx(m, nl)] = f2bf(v);
          else          C2[vtidx(m, nl)] = f2bf(v);
        } else if constexpr (EPI == 6) {
          ((u16*)Cv)[(size_t)m * (size_t)ldc + n] = ftof16(v);
        }
      }
    }
  }
}

// ---------------------------------------------------------------------------
// fused attention, wave-independent — proven form.
// ---------------------------------------------------------------------------
template<bool SELF>
__global__ __launch_bounds__(256)
void fused_attn(const u16* __restrict__ Qb, const u16* __restrict__ Kb,
                const u16* __restrict__ Vt, const u16* __restrict__ PE,
                const float* __restrict__ maskf, u16* __restrict__ O)
{
  __shared__ u16 SP[4][16][520];       // per-wave score strip
  __shared__ float rsm[4][16];         // per-wave 1/rowsum
  const int bid = blockIdx.y * 8 + blockIdx.x;
  const int g = (bid & 7) + 8 * ((bid >> 3) & 7);
  const int rt = bid >> 6;             // 0..7
  const int b = g >> 4, h = g & 15;
  const int tid = threadIdx.x, l = tid & 63, w = tid >> 6;
  const int ti = SELF ? (w * 8 + rt) : (rt * 4 + w);   // row-tile 0..31
  const int i0 = ti * 16;
  const int CT = SELF ? (i0 + 16) : 512;
  const int rsel = l & 15, kg = l >> 4;

  const u16* Qg = Qb + (size_t)g * 32768u;
  const u16* Kg = Kb + (size_t)g * 32768u;
  const u16* Vg = Vt + (size_t)g * 65536u;
  u16 (*sp)[520] = SP[w];
  float* rs = rsm[w];

  const s16x8 qf0 = *(const s16x8*)(Qg + (size_t)(i0 + rsel) * 64u + kg * 8);
  const s16x8 qf1 = *(const s16x8*)(Qg + (size_t)(i0 + rsel) * 64u + 32 + kg * 8);

  // ---- QK^T (+ mask + skew + causal) -> SP ----
  for (int j0 = 0; j0 < CT; j0 += 16) {
    const s16x8 kf0 = *(const s16x8*)(Kg + (size_t)(j0 + rsel) * 64u + kg * 8);
    const s16x8 kf1 = *(const s16x8*)(Kg + (size_t)(j0 + rsel) * 64u + 32 + kg * 8);
    f32x4 a = {0.f, 0.f, 0.f, 0.f};
    a = mfma16(qf0, kf0, a);
    a = mfma16(qf1, kf1, a);
    const int jj = j0 + rsel;                   // output col = l&15
    const float mj = maskf[b * 512 + jj];
#pragma unroll
    for (int e = 0; e < 4; ++e) {
      const int r = kg * 4 + e;                 // local q-row (output row)
      float v = a[e] + mj;
      if constexpr (SELF) {
        const int i = i0 + r;
        if (jj > i) v = NEG_INF;
        else        v += bf2f(PE[((size_t)(g * 512 + i)) * 512u + (511 + jj - i)]);
      }
      sp[r][jj] = f2bf(v);
    }
  }
  asm volatile("s_waitcnt lgkmcnt(0)" ::: "memory");
  __builtin_amdgcn_sched_barrier(0);

  // ---- softmax (wave-local): 4 lanes per row ----
  const int sr = l >> 2, sub = l & 3;
  float mx = NEG_INF;
  for (int c = sub * 4; c < CT; c += 16) {
    const u16x4 h4 = *(const u16x4*)&sp[sr][c];
#pragma unroll
    for (int e = 0; e < 4; ++e) mx = fmaxf(mx, bf2f(h4[e]));
  }
  mx = fmaxf(mx, __shfl_xor(mx, 1, 64));
  mx = fmaxf(mx, __shfl_xor(mx, 2, 64));
  float sum = 0.f;
  for (int c = sub * 4; c < CT; c += 16) {
    const u16x4 h4 = *(const u16x4*)&sp[sr][c];
    const float p0 = expf(bf2f(h4[0]) - mx), p1 = expf(bf2f(h4[1]) - mx);
    const float p2 = expf(bf2f(h4[2]) - mx), p3 = expf(bf2f(h4[3]) - mx);
    sum += p0 + p1 + p2 + p3;
    const u16x4 o4 = {f2bf(p0), f2bf(p1), f2bf(p2), f2bf(p3)};
    *(u16x4*)&sp[sr][c] = o4;                  // unnormalized P
  }
  sum += __shfl_xor(sum, 1, 64);
  sum += __shfl_xor(sum, 2, 64);
  if (sub == 0) rs[sr] = 1.f / sum;
  if (CT & 31) {                               // zero-pad P to 32-col boundary
    const u16x4 z = {0, 0, 0, 0};
    *(u16x4*)&sp[sr][CT + sub * 4] = z;
  }
  asm volatile("s_waitcnt lgkmcnt(0)" ::: "memory");
  __builtin_amdgcn_sched_barrier(0);

  // ---- PV: O[16][64] accumulated in registers ----
  f32x4 oa[4];
#pragma unroll
  for (int nt = 0; nt < 4; ++nt) oa[nt] = (f32x4){0.f, 0.f, 0.f, 0.f};
  const int nk = (CT + 31) >> 5;
  for (int kt = 0; kt < nk; ++kt) {
    const s16x8 pf = *(const s16x8*)&sp[rsel][kt * 32 + kg * 8];
#pragma unroll
    for (int nt = 0; nt < 4; ++nt) {
      const s16x8 vf = *(const s16x8*)(Vg + (size_t)(nt * 16 + rsel) * 512u + kt * 32 + kg * 8);
      oa[nt] = mfma16(pf, vf, oa[nt]);
    }
  }

  // ---- normalize + merged-head write ----
#pragma unroll
  for (int e = 0; e < 4; ++e) {
    const int q = kg * 4 + e;                  // local row
    const float inv = rs[q];
    u16* orow = O + ((size_t)(b * 512 + i0 + q)) * 1024u + h * 64;
#pragma unroll
    for (int nt = 0; nt < 4; ++nt)
      orow[nt * 16 + rsel] = f2bf(oa[nt][e] * inv);
  }
}

// ---------------------------------------------------------------------------
// split-K reduce + bias + residual(f32) + LayerNorm -> f32 Y + bf16 Yh
// ---------------------------------------------------------------------------
template<int KS>
__global__ __launch_bounds__(256)
void lnred_kernel(const float* __restrict__ P, const float* __restrict__ bias,
                  const float* __restrict__ R,
                  const float* __restrict__ gw, const float* __restrict__ bw,
                  float* __restrict__ Y, u16* __restrict__ Yh)
{
  __shared__ float sm[4];
  const int m = blockIdx.x, t = threadIdx.x, c = t * 4;
  float4 v = *(const float4*)(R + (size_t)m * 1024u + c);
  const float4 bb = *(const float4*)(bias + c);
  v.x += bb.x; v.y += bb.y; v.z += bb.z; v.w += bb.w;
#pragma unroll
  for (int s = 0; s < KS; ++s) {
    const float4 p = *(const float4*)(P + (size_t)s * 2097152u + (size_t)m * 1024u + c);
    v.x += p.x; v.y += p.y; v.z += p.z; v.w += p.w;
  }
  float srow = v.x + v.y + v.z + v.w;
  {  // block reduce sum
    const int lane = t & 63, wid = t >> 6;
    float r = srow;
#pragma unroll
    for (int o = 32; o > 0; o >>= 1) r += __shfl_down(r, o, 64);
    if (lane == 0) sm[wid] = r;
    __syncthreads();
    if (t == 0) sm[0] = sm[0] + sm[1] + sm[2] + sm[3];
    __syncthreads();
    srow = sm[0];
    __syncthreads();
  }
  const float mean = srow * (1.f / 1024.f);
  const float d0 = v.x - mean, d1 = v.y - mean, d2 = v.z - mean, d3 = v.w - mean;
  float q = d0 * d0 + d1 * d1 + d2 * d2 + d3 * d3;
  {
    const int lane = t & 63, wid = t >> 6;
    float r = q;
#pragma unroll
    for (int o = 32; o > 0; o >>= 1) r += __shfl_down(r, o, 64);
    if (lane == 0) sm[wid] = r;
    __syncthreads();
    if (t == 0) sm[0] = sm[0] + sm[1] + sm[2] + sm[3];
    __syncthreads();
    q = sm[0];
    __syncthreads();
  }
  const float rstd = rsqrtf(q * (1.f / 1024.f) + 1e-5f);
  float4 o;
  o.x = d0 * rstd * gw[c + 0] + bw[c + 0];
  o.y = d1 * rstd * gw[c + 1] + bw[c + 1];
  o.z = d2 * rstd * gw[c + 2] + bw[c + 2];
  o.w = d3 * rstd * gw[c + 3] + bw[c + 3];
  *(float4*)(Y + (size_t)m * 1024u + c) = o;
  const u16x4 h = {f2bf(o.x), f2bf(o.y), f2bf(o.z), f2bf(o.w)};
  *(u16x4*)(Yh + (size_t)m * 1024u + c) = h;
}

// ---------------------------------------------------------------------------
// transpose+convert f32[K,N] -> bf16[N,K], 64x64 tiles
// ---------------------------------------------------------------------------
static __device__ __forceinline__ void tconv_tile(const float* in, int N,
                                                  u16* out, int K, int k0, int n0) {
  __shared__ u16 L[64][72];
  const int t = threadIdx.x;
  const int rk = t >> 4, cn = (t & 15) * 4;
#pragma unroll
  for (int q = 0; q < 4; ++q) {
    const int kk = k0 + rk + q * 16;
    float4 v = *(const float4*)(in + (size_t)kk * (size_t)N + n0 + cn);
    L[cn + 0][rk + q * 16] = f2bf(v.x);
    L[cn + 1][rk + q * 16] = f2bf(v.y);
    L[cn + 2][rk + q * 16] = f2bf(v.z);
    L[cn + 3][rk + q * 16] = f2bf(v.w);
  }
  __syncthreads();
  const int rn = t >> 2, ck = (t & 3) * 16;
  u16* op = out + (size_t)(n0 + rn) * (size_t)K + k0 + ck;
  *(s16x8*)op       = *(const s16x8*)&L[rn][ck];
  *(s16x8*)(op + 8) = *(const s16x8*)&L[rn][ck + 8];
}

__global__ __launch_bounds__(256)
void conv_layer(const float* w0, const float* w1, const float* w2, const float* w3,
                const float* w4, const float* w5, const float* w6, const float* w7,
                const float* w8, const float* w9, u16* WT) {
  const int b = blockIdx.x;
  const float* in; u16* out; int N, K, kt, nt;
  if (b < 2048) {
    const int j = b >> 8, t = b & 255;
    const float* ws[8] = {w0, w1, w2, w3, w4, w5, w6, w7};
    in = ws[j]; out = WT + (size_t)j * 1048576u; K = 1024; N = 1024;
    kt = t >> 4; nt = t & 15;
  } else if (b < 3072) {
    const int t = b - 2048;
    in = w8; out = WT + 8388608u; K = 1024; N = 4096; kt = t >> 6; nt = t & 63;
  } else {
    const int t = b - 3072;
    in = w9; out = WT + 12582912u; K = 4096; N = 1024; kt = t >> 4; nt = t & 15;
  }
  tconv_tile(in, N, out, K, kt * 64, nt * 64);
}

__global__ __launch_bounds__(256)
void conv_wout(const float* in, u16* out) {
  const int b = blockIdx.x;            // 8000 = 16 ktiles * 500 ntiles
  const int kt = b / 500, nt = b % 500;
  tconv_tile(in, 32000, out, 1024, kt * 64, nt * 64);
}

// ---------------------------------------------------------------------------
// elementwise converts / masks
// ---------------------------------------------------------------------------
__global__ void conv_bf16(const float* __restrict__ in, u16* __restrict__ out) {
  const int i = (blockIdx.x * 256 + threadIdx.x) * 4;
  float4 v = *(const float4*)(in + i);
  u16x4 h = {f2bf(v.x), f2bf(v.y), f2bf(v.z), f2bf(v.w)};
  *(u16x4*)(out + i) = h;
}

__global__ void conv_pos(const float* __restrict__ pos, u16* __restrict__ posb) {
  const int idx = (blockIdx.x * 256 + threadIdx.x) * 4;   // over 6*512*64
  const int lyr = idx >> 15, rem = idx & 32767;
  float4 v = *(const float4*)(pos + (size_t)lyr * 65472u + rem);
  u16x4 h = {f2bf(v.x), f2bf(v.y), f2bf(v.z), f2bf(v.w)};
  *(u16x4*)(posb + idx) = h;
}

__global__ void mask_kernel(const int* __restrict__ dec, const int* __restrict__ enc,
                            float* __restrict__ mD, float* __restrict__ mE) {
  const int i = blockIdx.x * 256 + threadIdx.x;   // 2048
  mD[i] = (dec[i] == PADTOK) ? NEG_INF : 0.f;
  mE[i] = (enc[i] == PADTOK) ? NEG_INF : 0.f;
}

// ---------------------------------------------------------------------------
// reductions
// ---------------------------------------------------------------------------
static __device__ __forceinline__ float wred_sum(float v) {
#pragma unroll
  for (int o = 32; o > 0; o >>= 1) v += __shfl_down(v, o, 64);
  return v;
}
static __device__ __forceinline__ float wred_max(float v) {
#pragma unroll
  for (int o = 32; o > 0; o >>= 1) v = fmaxf(v, __shfl_down(v, o, 64));
  return v;
}

// ---------------------------------------------------------------------------
// small kernels
// ---------------------------------------------------------------------------
__global__ void embed_kernel(const int* __restrict__ dec, const float* __restrict__ emb,
                             float* __restrict__ X, u16* __restrict__ Xh) {
  const int m = blockIdx.x, t = threadIdx.x;
  const int tok = dec[m];
  float4 v = ((const float4*)(emb + (size_t)tok * 1024u))[t];
  ((float4*)(X + (size_t)m * 1024u))[t] = v;
  u16x4 h = {f2bf(v.x), f2bf(v.y), f2bf(v.z), f2bf(v.w)};
  *(u16x4*)(Xh + (size_t)m * 1024u + t * 4) = h;
}

// log_softmax over V=32000: f16 logits in first half of each f32 out row.
__global__ __launch_bounds__(512)
void log_softmax_kernel(float* __restrict__ out) {
  __shared__ u16 row[32000];
  __shared__ float sm[8];
  const int m = blockIdx.x, tid = threadIdx.x;
  const u16* src = (const u16*)out + (size_t)m * 64000u;
  for (int c = tid; c < 4000; c += 512)
    *(u16x8*)&row[c * 8] = *(const u16x8*)(src + c * 8);
  __syncthreads();
  float mx = NEG_INF;
  for (int c = tid; c < 4000; c += 512) {
    const u16x8 h = *(const u16x8*)&row[c * 8];
#pragma unroll
    for (int e = 0; e < 8; ++e) mx = fmaxf(mx, f16tof(h[e]));
  }
  mx = wred_max(mx);
  if ((tid & 63) == 0) sm[tid >> 6] = mx;
  __syncthreads();
  if (tid == 0) {
    float a = sm[0];
#pragma unroll
    for (int wI = 1; wI < 8; ++wI) a = fmaxf(a, sm[wI]);
    sm[0] = a;
  }
  __syncthreads();
  mx = sm[0];
  __syncthreads();
  float s = 0.f;
  for (int c = tid; c < 4000; c += 512) {
    const u16x8 h = *(const u16x8*)&row[c * 8];
#pragma unroll
    for (int e = 0; e < 8; ++e) s += expf(f16tof(h[e]) - mx);
  }
  s = wred_sum(s);
  if ((tid & 63) == 0) sm[tid >> 6] = s;
  __syncthreads();
  if (tid == 0) {
    float a = 0.f;
#pragma unroll
    for (int wI = 0; wI < 8; ++wI) a += sm[wI];
    sm[0] = a;
  }
  __syncthreads();
  const float lse = mx + logf(sm[0]);
  float* dst = out + (size_t)m * 32000u;
  for (int c = tid; c < 4000; c += 512) {
    const u16x8 h = *(const u16x8*)&row[c * 8];
    float4 o0, o1;
    o0.x = f16tof(h[0]) - lse; o0.y = f16tof(h[1]) - lse;
    o0.z = f16tof(h[2]) - lse; o0.w = f16tof(h[3]) - lse;
    o1.x = f16tof(h[4]) - lse; o1.y = f16tof(h[5]) - lse;
    o1.z = f16tof(h[6]) - lse; o1.w = f16tof(h[7]) - lse;
    ((float4*)dst)[c * 2]     = o0;
    ((float4*)dst)[c * 2 + 1] = o1;
  }
}

// ---------------------------------------------------------------------------
// host driver
// ---------------------------------------------------------------------------
extern "C" void kernel_launch(void* const* d_in, const int* in_sizes, int n_in,
                              void* d_out, int out_size, void* d_ws, size_t ws_size,
                              hipStream_t stream) {
  const float* enc_out = (const float*)d_in[0];
  const int*   dec_in  = (const int*)d_in[1];
  const int*   enc_in  = (const int*)d_in[2];
  const float* emb     = (const float*)d_in[3];
  const float* wq1 = (const float*)d_in[4];  const float* bq1 = (const float*)d_in[5];
  const float* wk1 = (const float*)d_in[6];  const float* bk1 = (const float*)d_in[7];
  const float* wv1 = (const float*)d_in[8];  const float* bv1 = (const float*)d_in[9];
  const float* wo1 = (const float*)d_in[10]; const float* bo1 = (const float*)d_in[11];
  const float* pos1 = (const float*)d_in[12];
  const float* wq2 = (const float*)d_in[13]; const float* bq2 = (const float*)d_in[14];
  const float* wk2 = (const float*)d_in[15]; const float* bk2 = (const float*)d_in[16];
  const float* wv2 = (const float*)d_in[17]; const float* bv2 = (const float*)d_in[18];
  const float* wo2 = (const float*)d_in[19]; const float* bo2 = (const float*)d_in[20];
  const float* ln1g = (const float*)d_in[21]; const float* ln1b = (const float*)d_in[22];
  const float* ln2g = (const float*)d_in[23]; const float* ln2b = (const float*)d_in[24];
  const float* ln3g = (const float*)d_in[25]; const float* ln3b = (const float*)d_in[26];
  const float* wf1 = (const float*)d_in[27]; const float* bf1 = (const float*)d_in[28];
  const float* wf2 = (const float*)d_in[29]; const float* bf2 = (const float*)d_in[30];
  const float* wout = (const float*)d_in[31]; const float* bout = (const float*)d_in[32];

  char* ws = (char*)d_ws;
  u16*   WT    = (u16*)(ws + 0);             // 32MB  per-layer transposed weights
  float* maskD = (float*)(ws + 33554432);    // 8KB
  float* maskE = (float*)(ws + 33562624);    // 8KB
  u16*   WoutT = (u16*)(ws + 0);             // 65.5MB, used only at the end
  u16*   PEP   = (u16*)(ws + 67108864);      // 32MB  PE bf16 (dead after fattn_self)
  float* Part  = (float*)(ws + 67108864);    // 32MB  split-K partials (reuses PEP)
  float* X     = (float*)(ws + 100663296);   // 8MB  f32 residual stream
  float* Xa    = (float*)(ws + 109051904);   // 8MB
  float* Xb    = (float*)(ws + 117440512);   // 8MB
  u16*   Ab16  = (u16*)(ws + 134217728);     // 4MB  current GEMM-input activation
  u16*   Q     = (u16*)(ws + 138412032);     // 4MB  [g][512][64]
  u16*   Kh    = (u16*)(ws + 142606336);     // 4MB  [g][512][64]
  u16*   VT    = (u16*)(ws + 146800640);     // 8MB  [g][128][512]
  u16*   Ob16  = (u16*)(ws + 155189248);     // 4MB  merged attn out
  u16*   FFH16 = (u16*)(ws + 159383552);     // 16MB [2048][4096]
  u16*   encb  = (u16*)(ws + 176160768);     // 4MB  encoder_outputs bf16
  u16*   posb  = (u16*)(ws + 180355072);     // 384KB [6][512][64]
  float* out   = (float*)d_out;

  embed_kernel<<<2048, 256, 0, stream>>>(dec_in, emb, X, Ab16);
  conv_bf16<<<2048, 256, 0, stream>>>(enc_out, encb);
  conv_pos<<<192, 256, 0, stream>>>(pos1, posb);
  mask_kernel<<<8, 256, 0, stream>>>(dec_in, enc_in, maskD, maskE);

  for (int i = 0; i < 6; ++i) {
    const size_t oHH = (size_t)i * 1048576u, oH = (size_t)i * 1024u;
    const float* bq1i = bq1 + oH; const float* bk1i = bk1 + oH;
    const float* bv1i = bv1 + oH; const float* bo1i = bo1 + oH;
    const float* bq2i = bq2 + oH; const float* bk2i = bk2 + oH;
    const float* bv2i = bv2 + oH; const float* bo2i = bo2 + oH;
    const float* bf1i = bf1 + (size_t)i * 4096u; const float* bf2i = bf2 + oH;
    const u16* posL = posb + (size_t)i * 32768u;

    conv_layer<<<4096, 256, 0, stream>>>(
        wq1 + oHH, wk1 + oHH, wv1 + oHH, wo1 + oHH,
        wq2 + oHH, wk2 + oHH, wv2 + oHH, wo2 + oHH,
        wf1 + (size_t)i * 4194304u, wf2 + (size_t)i * 4194304u, WT);

    // ---- self attention ----
    bgemm<4, true, 4, false, false, 0, 8, 1><<<dim3(24, 16, 1), 256, 0, stream>>>(
        Ab16, 0, WT, 0, bq1i, bk1i, bv1i, nullptr, Q, Kh, VT, 0, 0, 1024, 0.125f);
    bgemm<0, true, 4, false, false, 2, 8, 1><<<dim3(4, 256, 1), 256, 0, stream>>>(
        Q, 0, posL, 0, nullptr, nullptr, nullptr, nullptr, PEP, nullptr, nullptr,
        0, 512, 64, 1.f);
    fused_attn<true><<<dim3(8, 64), 256, 0, stream>>>(Q, Kh, VT, PEP, maskD, Ob16);
    // out-proj 1, split-K=2 -> f32 partials, then fused reduce+LN1
    bgemm<0, false, 2, false, false, 0, 8, 2><<<dim3(8, 32, 2), 256, 0, stream>>>(
        Ob16, 0, WT + 3145728u, 0, nullptr, nullptr, nullptr, nullptr,
        Part, nullptr, nullptr, 2097152, 1024, 1024, 1.f);
    lnred_kernel<2><<<2048, 256, 0, stream>>>(Part, bo1i, X, ln1g + oH, ln1b + oH, Xa, Ab16);

    // ---- cross attention ----
    bgemm<1, true, 2, false, false, 0, 8, 1><<<dim3(8, 32, 1), 256, 0, stream>>>(
        Ab16, 0, WT + 4194304u, 0, bq2i, nullptr, nullptr, nullptr, Q, nullptr, nullptr,
        0, 0, 1024, 0.125f);
    bgemm<5, true, 4, false, false, 0, 8, 1><<<dim3(16, 16, 1), 256, 0, stream>>>(
        encb, 0, WT + 5242880u, 0, bk2i, bv2i, nullptr, nullptr, Kh, VT, nullptr,
        0, 0, 1024, 1.f);
    fused_attn<false><<<dim3(8, 64), 256, 0, stream>>>(Q, Kh, VT, nullptr, maskE, Ob16);
    bgemm<0, false, 2, false, false, 0, 8, 2><<<dim3(8, 32, 2), 256, 0, stream>>>(
        Ob16, 0, WT + 7340032u, 0, nullptr, nullptr, nullptr, nullptr,
        Part, nullptr, nullptr, 2097152, 1024, 1024, 1.f);
    lnred_kernel<2><<<2048, 256, 0, stream>>>(Part, bo2i, Xa, ln2g + oH, ln2b + oH, Xb, Ab16);

    // ---- FFN ----
    bgemm<0, true, 4, true, false, 0, 8, 1><<<dim3(32, 16, 1), 256, 0, stream>>>(
        Ab16, 0, WT + 8388608u, 0, bf1i, nullptr, nullptr, nullptr, FFH16, nullptr, nullptr,
        0, 4096, 1024, 1.f);
    bgemm<0, false, 4, false, false, 0, 8, 4><<<dim3(8, 16, 4), 256, 0, stream>>>(
        FFH16, 0, WT + 12582912u, 0, nullptr, nullptr, nullptr, nullptr,
        Part, nullptr, nullptr, 2097152, 1024, 4096, 1.f);
    lnred_kernel<4><<<2048, 256, 0, stream>>>(Part, bf2i, Xb, ln3g + oH, ln3b + oH, X, Ab16);
  }

  // ---- output head (f16 logits into d_out row-halves) + log_softmax ----
  conv_wout<<<8000, 256, 0, stream>>>(wout, WoutT);
  bgemm<6, false, 4, false, false, 0, 16, 1><<<dim3(250, 16, 1), 256, 0, stream>>>(
      Ab16, 0, WoutT, 0, bout, nullptr, nullptr, nullptr, out, nullptr, nullptr,
      0, 64000, 1024, 1.f);
  log_softmax_kernel<<<2048, 512, 0, stream>>>(out);
}